// Round 6
// baseline (217.843 us; speedup 1.0000x reference)
//
#include <hip/hip_runtime.h>

#define NN 100
#define CC 256
#define NKK 103
#define LSA 72     // Abuf/Wbuf stride (bf16): 144 B rows, 16B-aligned frags
#define LDPW 136   // PW stride (bf16): 272 B rows, 16B-aligned frags
#define OTS 260    // out-transpose stride (f32): 1040 B rows, 16B-aligned

typedef __bf16 bf16;
typedef __bf16 bf16x4 __attribute__((ext_vector_type(4)));
typedef __bf16 bf16x8 __attribute__((ext_vector_type(8)));
typedef float f32x4 __attribute__((ext_vector_type(4)));

__global__ __launch_bounds__(512, 4)
void dysepconv_fused(const float* __restrict__ query,
                     const float* __restrict__ value,
                     const float* __restrict__ W,
                     const float* __restrict__ bwl,
                     const float* __restrict__ gamma,
                     const float* __restrict__ beta,
                     float* __restrict__ out)
{
    // LDS: PW 27200 + R 29232 + DW 1200 + RP 6400 + RS 800 = 64832 B (2 blocks/CU)
    __shared__ __align__(16) bf16 PW[NN * LDPW];                  // pw [n][m], cols 100..127 zeroed
    __shared__ __align__(16) bf16 R[100 * LSA + NKK * LSA];       // A: Abuf+Wbuf | D: OT (16x260 f32)
    __shared__ float DW[NN][3];
    __shared__ float RP[8][NN][2];
    __shared__ float RS[NN][2];

    bf16*  Abuf = R;                  // [100][LSA]
    bf16*  Wbuf = R + 100 * LSA;      // [103][LSA]  W^T chunk
    float* OT   = (float*)R;          // [16][OTS]   phase-D transpose tile

    const int t    = threadIdx.x;
    const int w    = t >> 6;          // wave 0..7
    const int lane = t & 63;
    const int ln16 = lane & 15;
    const int g    = lane >> 4;
    const int hi8  = g * 8;
    const int b    = blockIdx.x;

    const float* qb = query + (size_t)b * NN * CC;
    const float* vb = value + (size_t)b * NN * CC;

    // PW k-pad cols zeroed up-front (must be exact 0 for GEMM2's padded K);
    // ordered before epilogue-A writes by the phase-A barriers.
    for (int i = t; i < NN * 28; i += 512) {
        int r = i / 28, m = 100 + (i - (i / 28) * 28);
        PW[r * LDPW + m] = (bf16)0.f;
    }

    // ---------------- Phase A: dy = q @ W + bias ----------------
    f32x4 acc1[7];
    #pragma unroll
    for (int I = 0; I < 7; ++I) acc1[I] = (f32x4){0.f, 0.f, 0.f, 0.f};

    #pragma unroll 1   // rolled: keeps staging registers from being hoisted across chunks
    for (int kc = 0; kc < 4; ++kc) {
        const int k0 = kc * 64;
        __syncthreads();                       // prior chunk's LDS reads complete
        {   // query chunk: 1600 f32x4 items, coalesced, one drain
            f32x4 qv[4];
            #pragma unroll
            for (int p = 0; p < 4; ++p) {
                int idx = p * 512 + t;
                if (idx < 1600) {
                    int r = idx >> 4, j = (idx & 15) << 2;
                    qv[p] = *(const f32x4*)(qb + r * CC + k0 + j);
                }
            }
            #pragma unroll
            for (int p = 0; p < 4; ++p) {
                int idx = p * 512 + t;
                if (idx < 1600) {
                    int r = idx >> 4, j = (idx & 15) << 2;
                    bf16x4 s;
                    #pragma unroll
                    for (int i = 0; i < 4; ++i) s[i] = (bf16)qv[p][i];
                    *(bf16x4*)&Abuf[r * LSA + j] = s;
                }
            }
        }
        {   // W chunk: 64x103 scalar items, coalesced load, transposed scatter
            float wv[13];
            #pragma unroll
            for (int p = 0; p < 13; ++p) {
                int idx = p * 512 + t;
                if (idx < 64 * NKK) {
                    int kk = idx / NKK, ka = idx - kk * NKK;
                    wv[p] = W[(size_t)(k0 + kk) * NKK + ka];
                }
            }
            #pragma unroll
            for (int p = 0; p < 13; ++p) {
                int idx = p * 512 + t;
                if (idx < 64 * NKK) {
                    int kk = idx / NKK, ka = idx - kk * NKK;
                    Wbuf[ka * LSA + kk] = (bf16)wv[p];
                }
            }
        }
        __syncthreads();

        if (w < 7) {
            const int rB = (w * 16 + ln16 < NKK) ? (w * 16 + ln16) : (NKK - 1); // clamp: cols>=103 discarded
            #pragma unroll
            for (int s = 0; s < 2; ++s) {
                bf16x8 bv = *(const bf16x8*)&Wbuf[rB * LSA + s * 32 + hi8];
                #pragma unroll
                for (int I = 0; I < 7; ++I) {
                    int row = I * 16 + ln16;
                    row = (row < NN) ? row : (NN - 1);   // clamp: rows>=100 discarded
                    bf16x8 av = *(const bf16x8*)&Abuf[row * LSA + s * 32 + hi8];
                    acc1[I] = __builtin_amdgcn_mfma_f32_16x16x32_bf16(av, bv, acc1[I], 0, 0, 0);
                }
            }
        }
    }
    __syncthreads();   // last chunk's Abuf/Wbuf reads done (R reused by OT later)

    // epilogue A: write pw (bf16) / dw (fp32)
    if (w < 7) {
        const int kap = w * 16 + ln16;
        const float bw = (kap < NKK) ? bwl[kap] : 0.f;
        #pragma unroll
        for (int I = 0; I < 7; ++I) {
            #pragma unroll
            for (int r = 0; r < 4; ++r) {
                int n = I * 16 + g * 4 + r;
                if (n < NN && kap < NKK) {
                    float v = acc1[I][r] + bw;
                    if (kap < 3) DW[n][kap] = v;
                    else         PW[n * LDPW + (kap - 3)] = (bf16)v;
                }
            }
        }
    }
    __syncthreads();   // PW/DW visible

    // ---------------- Phase B/C: conv (register B-layout, batched loads) + GEMM2 ----------------
    f32x4 acc2[2][7];
    #pragma unroll
    for (int st = 0; st < 2; ++st)
        #pragma unroll
        for (int I = 0; I < 7; ++I) acc2[st][I] = (f32x4){0.f, 0.f, 0.f, 0.f};

    const int cb = w * 16 + ln16;    // st0: cb (0..127), st1: cb+128
    #pragma unroll 1   // rolled: one 16-load batch in flight per iteration, no cross-iter hoist
    for (int ks = 0; ks < 4; ++ks) {
        // batch all 16 value loads for this ks, one drain
        float xv[8], yv[8];
        #pragma unroll
        for (int j = 0; j < 8; ++j) {
            int m = ks * 32 + hi8 + j;
            bool mv = (m < NN);
            const float* vr = vb + m * CC;
            xv[j] = mv ? vr[cb]       : 0.f;
            yv[j] = mv ? vr[cb + 128] : 0.f;
        }
        bf16x8 dv0, dv1;
        #pragma unroll
        for (int j = 0; j < 8; ++j) {
            int  m  = ks * 32 + hi8 + j;
            bool mv = (m < NN);
            int  mc = mv ? m : (NN - 1);
            float w0 = DW[mc][0], w1 = DW[mc][1], w2 = DW[mc][2];
            float x0 = xv[j], y0 = yv[j];
            float xm = __shfl(x0, (lane - 1) & 63), xp = __shfl(x0, (lane + 1) & 63);
            float ym = __shfl(y0, (lane - 1) & 63), yp = __shfl(y0, (lane + 1) & 63);
            if (ln16 == 0) {
                xm = (mv && cb > 0) ? vb[m * CC + cb - 1] : 0.f;
                ym = mv ? vb[m * CC + cb + 127] : 0.f;
            }
            if (ln16 == 15) {
                xp = mv ? vb[m * CC + cb + 1] : 0.f;
                yp = (mv && cb + 129 < CC) ? vb[m * CC + cb + 129] : 0.f;
            }
            float d0 = w0 * xm + w1 * x0 + w2 * xp;
            float d1 = w0 * ym + w1 * y0 + w2 * yp;
            dv0[j] = (bf16)(mv ? fmaxf(d0, 0.f) : 0.f);
            dv1[j] = (bf16)(mv ? fmaxf(d1, 0.f) : 0.f);
        }
        #pragma unroll
        for (int I = 0; I < 7; ++I) {
            int row = I * 16 + ln16;
            row = (row < NN) ? row : (NN - 1);   // PW has 100 rows; clamped rows discarded
            bf16x8 af = *(const bf16x8*)&PW[row * LDPW + ks * 32 + hi8];
            acc2[0][I] = __builtin_amdgcn_mfma_f32_16x16x32_bf16(af, dv0, acc2[0][I], 0, 0, 0);
            acc2[1][I] = __builtin_amdgcn_mfma_f32_16x16x32_bf16(af, dv1, acc2[1][I], 0, 0, 0);
        }
    }

    // ---------------- Phase D: LayerNorm ----------------
    #pragma unroll
    for (int I = 0; I < 7; ++I) {
        #pragma unroll
        for (int r = 0; r < 4; ++r) {
            float a = acc2[0][I][r], e = acc2[1][I][r];
            float s1 = a + e, s2 = a * a + e * e;
            #pragma unroll
            for (int mk = 1; mk < 16; mk <<= 1) {
                s1 += __shfl_xor(s1, mk);
                s2 += __shfl_xor(s2, mk);
            }
            int n = I * 16 + g * 4 + r;
            if (ln16 == 0 && n < NN) {
                RP[w][n][0] = s1;
                RP[w][n][1] = s2;
            }
        }
    }
    __syncthreads();
    if (t < NN) {
        float S1 = 0.f, S2 = 0.f;
        #pragma unroll
        for (int wi = 0; wi < 8; ++wi) { S1 += RP[wi][t][0]; S2 += RP[wi][t][1]; }
        float mu  = S1 * (1.f / 256.f);
        float var = S2 * (1.f / 256.f) - mu * mu;
        RS[t][0] = mu;
        RS[t][1] = rsqrtf(fmaxf(var, 0.f) + 1e-5f);
    }
    __syncthreads();

    // normalize + transpose through LDS -> coalesced f32x4 stores
    const float gm0 = gamma[cb], gm1 = gamma[cb + 128];
    const float bt0 = beta[cb],  bt1 = beta[cb + 128];
    float* ob = out + (size_t)b * NN * CC;
    #pragma unroll
    for (int I = 0; I < 7; ++I) {
        #pragma unroll
        for (int r = 0; r < 4; ++r) {
            int n = I * 16 + g * 4 + r;
            if (n < NN) {
                float mu = RS[n][0], rs = RS[n][1];
                int rt = g * 4 + r;
                OT[rt * OTS + cb]       = (acc2[0][I][r] - mu) * rs * gm0 + bt0;
                OT[rt * OTS + cb + 128] = (acc2[1][I][r] - mu) * rs * gm1 + bt1;
            }
        }
        __syncthreads();
        #pragma unroll
        for (int p = 0; p < 2; ++p) {
            int idx  = p * 512 + t;          // 16 rows x 64 f32x4
            int row  = idx >> 6, c4 = (idx & 63) << 2;
            int grow = I * 16 + row;
            if (grow < NN)
                *(f32x4*)(ob + grow * CC + c4) = *(const f32x4*)&OT[row * OTS + c4];
        }
        __syncthreads();
    }
}

extern "C" void kernel_launch(void* const* d_in, const int* in_sizes, int n_in,
                              void* d_out, int out_size, void* d_ws, size_t ws_size,
                              hipStream_t stream) {
    const float* query = (const float*)d_in[0];
    const float* value = (const float*)d_in[1];
    const float* W     = (const float*)d_in[2];
    const float* bwl   = (const float*)d_in[3];
    const float* gamma = (const float*)d_in[4];
    const float* beta  = (const float*)d_in[5];
    dysepconv_fused<<<dim3(512), dim3(512), 0, stream>>>(query, value, W, bwl, gamma, beta, (float*)d_out);
}